// Round 4
// baseline (395.072 us; speedup 1.0000x reference)
//
#include <hip/hip_runtime.h>
#include <hip/hip_bf16.h>

// RGCN: N=50000, R=16, H=32, L=8, E=1600000. Float tensors f32; h1 fp16.
// Round 13: build rewritten as global-atomic count/scan/scatter (contention
// is trivial: 800K bins, mean 2 edges/bin). Deletes p2sort + all LDS
// staging/ranking; edge-data passes 4 -> 2. combo keeps the (ofs<<8)|cnt
// packing so the (unchanged) layer kernels are bit-compatible.
// Layers (rounds 10-12): wave-per-dst, 32 edges in flight (4 pipelined
// gather clusters), layer2 inner loop on v_dot2_f32_f16 with W2/root2 in
// LDS as fp16 h-pairs (rows padded to 20 dwords).
#define Nn 50000
#define Rr 16
#define Hh 32
#define Ll 8
#define Ee 1600000
#define NSEG 800000
#define NI4 200000      // NSEG/4
#define NBLK_SC 782     // ceil(NI4/256)
#define W2U 20          // LDS row stride in dwords (16 used + 4 pad)

typedef _Float16 h2 __attribute__((ext_vector_type(2)));

__device__ __forceinline__ float dot2(h2 a, unsigned b, float c) {
#ifdef __AMDGCN__
    return __builtin_amdgcn_fdot2(a, __builtin_bit_cast(h2, b), c, false);
#else
    h2 hb = __builtin_bit_cast(h2, b);
    return fmaf((float)a[0], (float)hb[0],
                fmaf((float)a[1], (float)hb[1], c));
#endif
}

// ---- count: per-(dst,r) segment histogram via global atomics ----
__global__ __launch_bounds__(256) void count_kernel(
        const int* __restrict__ dst, const int* __restrict__ etype,
        int* __restrict__ counts) {
    int i = blockIdx.x * 256 + threadIdx.x;       // int4 index over E/4
    if (i >= Ee / 4) return;
    int4 d4 = ((const int4*)dst)[i];
    int4 e4 = ((const int4*)etype)[i];
    atomicAdd(&counts[(d4.x << 4) | e4.x], 1);
    atomicAdd(&counts[(d4.y << 4) | e4.y], 1);
    atomicAdd(&counts[(d4.z << 4) | e4.z], 1);
    atomicAdd(&counts[(d4.w << 4) | e4.w], 1);
}

// ---- scanA: per-1024-chunk exclusive prefix of counts (in place) ----
__global__ __launch_bounds__(256) void scanA_kernel(
        int4* data4, int* __restrict__ bsum) {
    __shared__ int sm[256];
    int i4 = blockIdx.x * 256 + threadIdx.x;
    int4 v = make_int4(0, 0, 0, 0);
    if (i4 < NI4) v = data4[i4];
    int s0 = v.x, s1 = s0 + v.y, s2 = s1 + v.z, s3 = s2 + v.w;
    sm[threadIdx.x] = s3;
    __syncthreads();
    for (int off = 1; off < 256; off <<= 1) {
        int add = (threadIdx.x >= off) ? sm[threadIdx.x - off] : 0;
        __syncthreads();
        sm[threadIdx.x] += add;
        __syncthreads();
    }
    int base = sm[threadIdx.x] - s3;
    if (i4 < NI4)
        data4[i4] = make_int4(base, base + s0, base + s1, base + s2);
    if (threadIdx.x == 255) bsum[blockIdx.x] = sm[255];
}

// ---- scanB: exclusive prefix of chunk totals ----
__global__ __launch_bounds__(1024) void scanB_kernel(
        const int* __restrict__ bsum, int* __restrict__ boff, int nblk) {
    __shared__ int sm[1024];
    int v = (threadIdx.x < nblk) ? bsum[threadIdx.x] : 0;
    sm[threadIdx.x] = v;
    __syncthreads();
    for (int off = 1; off < 1024; off <<= 1) {
        int add = (threadIdx.x >= off) ? sm[threadIdx.x - off] : 0;
        __syncthreads();
        sm[threadIdx.x] += add;
        __syncthreads();
    }
    if (threadIdx.x < nblk) boff[threadIdx.x] = sm[threadIdx.x] - v;
}

// ---- fixup: combo[seg]=(global_ofs<<8)|cnt ; cur[seg]=global_ofs ----
__global__ __launch_bounds__(256) void fixup_kernel(
        const int4* __restrict__ data4, const int* __restrict__ boff,
        unsigned* __restrict__ combo, int* __restrict__ cur) {
    int i4 = blockIdx.x * 256 + threadIdx.x;
    if (i4 >= NI4) return;
    int b = boff[i4 >> 8];
    int4 v = data4[i4];
    int o0 = v.x + b, o1 = v.y + b, o2 = v.z + b, o3 = v.w + b;
    int o4;
    if (i4 == NI4 - 1) {
        o4 = Ee;
    } else {
        int nb = boff[(i4 + 1) >> 8];
        o4 = data4[i4 + 1].x + nb;
    }
    int s = i4 << 2;
    combo[s]     = ((unsigned)o0 << 8) | (unsigned)(o1 - o0);
    combo[s + 1] = ((unsigned)o1 << 8) | (unsigned)(o2 - o1);
    combo[s + 2] = ((unsigned)o2 << 8) | (unsigned)(o3 - o2);
    combo[s + 3] = ((unsigned)o3 << 8) | (unsigned)(o4 - o3);
    ((int4*)cur)[i4] = make_int4(o0, o1, o2, o3);
    if (i4 == 0) combo[NSEG] = ((unsigned)Ee) << 8;
}

// ---- scatter: csr32[pos] = (r<<24)|(cnt<<16)|src, pos via atomic cursor ----
__global__ __launch_bounds__(256) void scatter_kernel(
        const int* __restrict__ src, const int* __restrict__ dst,
        const int* __restrict__ etype, const unsigned* __restrict__ combo,
        int* __restrict__ cur, unsigned* __restrict__ csr32) {
    int i = blockIdx.x * 256 + threadIdx.x;       // int4 index over E/4
    if (i >= Ee / 4) return;
    int4 s4 = ((const int4*)src)[i];
    int4 d4 = ((const int4*)dst)[i];
    int4 e4 = ((const int4*)etype)[i];
    {
        int seg = (d4.x << 4) | e4.x;
        int pos = atomicAdd(&cur[seg], 1);
        unsigned cnt = combo[seg] & 255u;
        csr32[pos] = ((unsigned)e4.x << 24) | (cnt << 16) | (unsigned)s4.x;
    }
    {
        int seg = (d4.y << 4) | e4.y;
        int pos = atomicAdd(&cur[seg], 1);
        unsigned cnt = combo[seg] & 255u;
        csr32[pos] = ((unsigned)e4.y << 24) | (cnt << 16) | (unsigned)s4.y;
    }
    {
        int seg = (d4.z << 4) | e4.z;
        int pos = atomicAdd(&cur[seg], 1);
        unsigned cnt = combo[seg] & 255u;
        csr32[pos] = ((unsigned)e4.z << 24) | (cnt << 16) | (unsigned)s4.z;
    }
    {
        int seg = (d4.w << 4) | e4.w;
        int pos = atomicAdd(&cur[seg], 1);
        unsigned cnt = combo[seg] & 255u;
        csr32[pos] = ((unsigned)e4.w << 24) | (cnt << 16) | (unsigned)s4.w;
    }
}

// ---- layer 1: wave per dst; 32 edges in flight (4 pipelined clusters) ----
__global__ __launch_bounds__(256) void layer1_kernel(
        const unsigned* __restrict__ csr32, const unsigned* __restrict__ combo,
        const float* __restrict__ W1, const float* __restrict__ root1,
        const float* __restrict__ b1, unsigned short* __restrict__ h1h) {
    int d = (blockIdx.x * 256 + threadIdx.x) >> 6;
    int lane = threadIdx.x & 63;
    int slot = lane >> 3, chunk = lane & 7;
    if (d >= Nn) return;
    int beg = (int)(combo[d << 4] >> 8);
    int end = (int)(combo[(d + 1) << 4] >> 8);
    int deg = end - beg;
    float4 acc = make_float4(0.f, 0.f, 0.f, 0.f);
    const float* Wc = W1 + (chunk << 2);
#pragma unroll 1
    for (int i = 0; i < deg; i += 32) {
        int p0 = i + slot, p1 = p0 + 8, p2 = p0 + 16, p3 = p0 + 24;
        bool r0 = p0 < deg, r1 = p1 < deg, r2 = p2 < deg, r3 = p3 < deg;
        unsigned v0 = csr32[beg + (r0 ? p0 : 0)];
        unsigned v1 = csr32[beg + (r1 ? p1 : 0)];
        unsigned v2 = csr32[beg + (r2 ? p2 : 0)];
        unsigned v3 = csr32[beg + (r3 ? p3 : 0)];
        float n0 = r0 ? __builtin_amdgcn_rcpf((float)((v0 >> 16) & 255u)) : 0.f;
        float n1 = r1 ? __builtin_amdgcn_rcpf((float)((v1 >> 16) & 255u)) : 0.f;
        float n2 = r2 ? __builtin_amdgcn_rcpf((float)((v2 >> 16) & 255u)) : 0.f;
        float n3 = r3 ? __builtin_amdgcn_rcpf((float)((v3 >> 16) & 255u)) : 0.f;
        float4 w0 = *(const float4*)(Wc +
            ((size_t)((int)(v0 >> 24) * Nn + (int)(v0 & 0xffffu)) << 5));
        float4 w1 = *(const float4*)(Wc +
            ((size_t)((int)(v1 >> 24) * Nn + (int)(v1 & 0xffffu)) << 5));
        float4 w2 = *(const float4*)(Wc +
            ((size_t)((int)(v2 >> 24) * Nn + (int)(v2 & 0xffffu)) << 5));
        float4 w3 = *(const float4*)(Wc +
            ((size_t)((int)(v3 >> 24) * Nn + (int)(v3 & 0xffffu)) << 5));
        acc.x = fmaf(n0, w0.x, acc.x); acc.y = fmaf(n0, w0.y, acc.y);
        acc.z = fmaf(n0, w0.z, acc.z); acc.w = fmaf(n0, w0.w, acc.w);
        acc.x = fmaf(n1, w1.x, acc.x); acc.y = fmaf(n1, w1.y, acc.y);
        acc.z = fmaf(n1, w1.z, acc.z); acc.w = fmaf(n1, w1.w, acc.w);
        acc.x = fmaf(n2, w2.x, acc.x); acc.y = fmaf(n2, w2.y, acc.y);
        acc.z = fmaf(n2, w2.z, acc.z); acc.w = fmaf(n2, w2.w, acc.w);
        acc.x = fmaf(n3, w3.x, acc.x); acc.y = fmaf(n3, w3.y, acc.y);
        acc.z = fmaf(n3, w3.z, acc.z); acc.w = fmaf(n3, w3.w, acc.w);
    }
#pragma unroll
    for (int m = 8; m <= 32; m <<= 1) {
        acc.x += __shfl_xor(acc.x, m, 64);
        acc.y += __shfl_xor(acc.y, m, 64);
        acc.z += __shfl_xor(acc.z, m, 64);
        acc.w += __shfl_xor(acc.w, m, 64);
    }
    if (slot == 0) {
        int hb = chunk << 2;
        float4 rt = *(const float4*)(root1 + (d << 5) + hb);
        float4 bb = *(const float4*)(b1 + hb);
        _Float16 q0 = (_Float16)fmaxf(acc.x + rt.x + bb.x, 0.f);
        _Float16 q1 = (_Float16)fmaxf(acc.y + rt.y + bb.y, 0.f);
        _Float16 q2 = (_Float16)fmaxf(acc.z + rt.z + bb.z, 0.f);
        _Float16 q3 = (_Float16)fmaxf(acc.w + rt.w + bb.w, 0.f);
        ushort4 ov;
        ov.x = __builtin_bit_cast(unsigned short, q0);
        ov.y = __builtin_bit_cast(unsigned short, q1);
        ov.z = __builtin_bit_cast(unsigned short, q2);
        ov.w = __builtin_bit_cast(unsigned short, q3);
        *(ushort4*)(h1h + (d << 5) + hb) = ov;
    }
}

// ---- layer 2: wave per dst; 32 edges in flight; fdot2 fp16 MAC (LDS) ----
__global__ __launch_bounds__(256) void layer2_kernel(
        const unsigned* __restrict__ csr32, const unsigned* __restrict__ combo,
        const unsigned short* __restrict__ h1h, const float* __restrict__ W2,
        const float* __restrict__ root2, const float* __restrict__ b2,
        float* __restrict__ out) {
    // W2s[(r*8+c)*W2U + hp*8 + l] = half2(W2[r][4c+2hp][l], W2[r][4c+2hp+1][l])
    // r==16 row holds root2. 16 dwords used per row, stride 20 (80B, 16B-aligned).
    __shared__ unsigned W2s[17 * 8 * W2U];
    for (int idx = threadIdx.x; idx < 17 * 8 * 16; idx += 256) {
        int r = idx >> 7;
        int c = (idx >> 4) & 7;
        int u = idx & 15;
        int hp = u >> 3, l = u & 7;
        int hh = (c << 2) | (hp << 1);
        float w0, w1;
        if (r < 16) {
            w0 = W2[(r << 8) + (hh << 3) + l];
            w1 = W2[(r << 8) + ((hh + 1) << 3) + l];
        } else {
            w0 = root2[(hh << 3) + l];
            w1 = root2[((hh + 1) << 3) + l];
        }
        h2 p = { (_Float16)w0, (_Float16)w1 };
        W2s[((r << 3) | c) * W2U + u] = __builtin_bit_cast(unsigned, p);
    }
    __syncthreads();

    int d = (blockIdx.x * 256 + threadIdx.x) >> 6;
    int lane = threadIdx.x & 63;
    int slot = lane >> 3, chunk = lane & 7;
    if (d >= Nn) return;
    int beg = (int)(combo[d << 4] >> 8);
    int end = (int)(combo[(d + 1) << 4] >> 8);
    int deg = end - beg;
    int degv = deg + 1;                 // + virtual root2 edge
    float acc[8] = {0.f, 0.f, 0.f, 0.f, 0.f, 0.f, 0.f, 0.f};
    const int hb = chunk << 2;
#pragma unroll 1
    for (int i = 0; i < degv; i += 32) {
        int p0 = i + slot, p1 = p0 + 8, p2 = p0 + 16, p3 = p0 + 24;
        bool re0 = p0 < deg, re1 = p1 < deg, re2 = p2 < deg, re3 = p3 < deg;
        bool vi0 = p0 == deg, vi1 = p1 == deg, vi2 = p2 == deg, vi3 = p3 == deg;
        unsigned v0 = csr32[beg + (re0 ? p0 : 0)];
        unsigned v1 = csr32[beg + (re1 ? p1 : 0)];
        unsigned v2 = csr32[beg + (re2 ? p2 : 0)];
        unsigned v3 = csr32[beg + (re3 ? p3 : 0)];
        int s0 = vi0 ? d : (re0 ? (int)(v0 & 0xffffu) : 0);
        int s1 = vi1 ? d : (re1 ? (int)(v1 & 0xffffu) : 0);
        int s2 = vi2 ? d : (re2 ? (int)(v2 & 0xffffu) : 0);
        int s3 = vi3 ? d : (re3 ? (int)(v3 & 0xffffu) : 0);
        int r0 = vi0 ? 16 : (re0 ? (int)(v0 >> 24) : 0);
        int r1 = vi1 ? 16 : (re1 ? (int)(v1 >> 24) : 0);
        int r2 = vi2 ? 16 : (re2 ? (int)(v2 >> 24) : 0);
        int r3 = vi3 ? 16 : (re3 ? (int)(v3 >> 24) : 0);
        float n0 = vi0 ? 1.0f
                 : (re0 ? __builtin_amdgcn_rcpf((float)((v0 >> 16) & 255u)) : 0.f);
        float n1 = vi1 ? 1.0f
                 : (re1 ? __builtin_amdgcn_rcpf((float)((v1 >> 16) & 255u)) : 0.f);
        float n2 = vi2 ? 1.0f
                 : (re2 ? __builtin_amdgcn_rcpf((float)((v2 >> 16) & 255u)) : 0.f);
        float n3 = vi3 ? 1.0f
                 : (re3 ? __builtin_amdgcn_rcpf((float)((v3 >> 16) & 255u)) : 0.f);
        uint2 hw0 = *(const uint2*)(h1h + (s0 << 5) + hb);
        uint2 hw1 = *(const uint2*)(h1h + (s1 << 5) + hb);
        uint2 hw2 = *(const uint2*)(h1h + (s2 << 5) + hb);
        uint2 hw3 = *(const uint2*)(h1h + (s3 << 5) + hb);
        const unsigned* w0p = &W2s[((r0 << 3) | chunk) * W2U];
        const unsigned* w1p = &W2s[((r1 << 3) | chunk) * W2U];
        const unsigned* w2p = &W2s[((r2 << 3) | chunk) * W2U];
        const unsigned* w3p = &W2s[((r3 << 3) | chunk) * W2U];

        h2 n0h = { (_Float16)n0, (_Float16)n0 };
        h2 a00 = __builtin_bit_cast(h2, hw0.x) * n0h;
        h2 a01 = __builtin_bit_cast(h2, hw0.y) * n0h;
        uint4 b00 = *(const uint4*)(w0p);
        uint4 b01 = *(const uint4*)(w0p + 4);
        uint4 b02 = *(const uint4*)(w0p + 8);
        uint4 b03 = *(const uint4*)(w0p + 12);
        acc[0] = dot2(a00, b00.x, acc[0]); acc[1] = dot2(a00, b00.y, acc[1]);
        acc[2] = dot2(a00, b00.z, acc[2]); acc[3] = dot2(a00, b00.w, acc[3]);
        acc[4] = dot2(a00, b01.x, acc[4]); acc[5] = dot2(a00, b01.y, acc[5]);
        acc[6] = dot2(a00, b01.z, acc[6]); acc[7] = dot2(a00, b01.w, acc[7]);
        acc[0] = dot2(a01, b02.x, acc[0]); acc[1] = dot2(a01, b02.y, acc[1]);
        acc[2] = dot2(a01, b02.z, acc[2]); acc[3] = dot2(a01, b02.w, acc[3]);
        acc[4] = dot2(a01, b03.x, acc[4]); acc[5] = dot2(a01, b03.y, acc[5]);
        acc[6] = dot2(a01, b03.z, acc[6]); acc[7] = dot2(a01, b03.w, acc[7]);

        h2 n1h = { (_Float16)n1, (_Float16)n1 };
        h2 a10 = __builtin_bit_cast(h2, hw1.x) * n1h;
        h2 a11 = __builtin_bit_cast(h2, hw1.y) * n1h;
        uint4 b10 = *(const uint4*)(w1p);
        uint4 b11 = *(const uint4*)(w1p + 4);
        uint4 b12 = *(const uint4*)(w1p + 8);
        uint4 b13 = *(const uint4*)(w1p + 12);
        acc[0] = dot2(a10, b10.x, acc[0]); acc[1] = dot2(a10, b10.y, acc[1]);
        acc[2] = dot2(a10, b10.z, acc[2]); acc[3] = dot2(a10, b10.w, acc[3]);
        acc[4] = dot2(a10, b11.x, acc[4]); acc[5] = dot2(a10, b11.y, acc[5]);
        acc[6] = dot2(a10, b11.z, acc[6]); acc[7] = dot2(a10, b11.w, acc[7]);
        acc[0] = dot2(a11, b12.x, acc[0]); acc[1] = dot2(a11, b12.y, acc[1]);
        acc[2] = dot2(a11, b12.z, acc[2]); acc[3] = dot2(a11, b12.w, acc[3]);
        acc[4] = dot2(a11, b13.x, acc[4]); acc[5] = dot2(a11, b13.y, acc[5]);
        acc[6] = dot2(a11, b13.z, acc[6]); acc[7] = dot2(a11, b13.w, acc[7]);

        h2 n2h = { (_Float16)n2, (_Float16)n2 };
        h2 a20 = __builtin_bit_cast(h2, hw2.x) * n2h;
        h2 a21 = __builtin_bit_cast(h2, hw2.y) * n2h;
        uint4 b20 = *(const uint4*)(w2p);
        uint4 b21 = *(const uint4*)(w2p + 4);
        uint4 b22 = *(const uint4*)(w2p + 8);
        uint4 b23 = *(const uint4*)(w2p + 12);
        acc[0] = dot2(a20, b20.x, acc[0]); acc[1] = dot2(a20, b20.y, acc[1]);
        acc[2] = dot2(a20, b20.z, acc[2]); acc[3] = dot2(a20, b20.w, acc[3]);
        acc[4] = dot2(a20, b21.x, acc[4]); acc[5] = dot2(a20, b21.y, acc[5]);
        acc[6] = dot2(a20, b21.z, acc[6]); acc[7] = dot2(a20, b21.w, acc[7]);
        acc[0] = dot2(a21, b22.x, acc[0]); acc[1] = dot2(a21, b22.y, acc[1]);
        acc[2] = dot2(a21, b22.z, acc[2]); acc[3] = dot2(a21, b22.w, acc[3]);
        acc[4] = dot2(a21, b23.x, acc[4]); acc[5] = dot2(a21, b23.y, acc[5]);
        acc[6] = dot2(a21, b23.z, acc[6]); acc[7] = dot2(a21, b23.w, acc[7]);

        h2 n3h = { (_Float16)n3, (_Float16)n3 };
        h2 a30 = __builtin_bit_cast(h2, hw3.x) * n3h;
        h2 a31 = __builtin_bit_cast(h2, hw3.y) * n3h;
        uint4 b30 = *(const uint4*)(w3p);
        uint4 b31 = *(const uint4*)(w3p + 4);
        uint4 b32 = *(const uint4*)(w3p + 8);
        uint4 b33 = *(const uint4*)(w3p + 12);
        acc[0] = dot2(a30, b30.x, acc[0]); acc[1] = dot2(a30, b30.y, acc[1]);
        acc[2] = dot2(a30, b30.z, acc[2]); acc[3] = dot2(a30, b30.w, acc[3]);
        acc[4] = dot2(a30, b31.x, acc[4]); acc[5] = dot2(a30, b31.y, acc[5]);
        acc[6] = dot2(a30, b31.z, acc[6]); acc[7] = dot2(a30, b31.w, acc[7]);
        acc[0] = dot2(a31, b32.x, acc[0]); acc[1] = dot2(a31, b32.y, acc[1]);
        acc[2] = dot2(a31, b32.z, acc[2]); acc[3] = dot2(a31, b32.w, acc[3]);
        acc[4] = dot2(a31, b33.x, acc[4]); acc[5] = dot2(a31, b33.y, acc[5]);
        acc[6] = dot2(a31, b33.z, acc[6]); acc[7] = dot2(a31, b33.w, acc[7]);
    }
#pragma unroll
    for (int m = 1; m <= 32; m <<= 1) {
#pragma unroll
        for (int l = 0; l < 8; ++l)
            acc[l] += __shfl_xor(acc[l], m, 64);
    }
    if (lane < 8) {
        float myv = acc[0];
#pragma unroll
        for (int l = 1; l < 8; ++l) myv = (lane == l) ? acc[l] : myv;
        float o = myv + b2[lane];
        out[(d << 3) | lane] = 1.0f / (1.0f + __expf(-o));
    }
}

extern "C" void kernel_launch(void* const* d_in, const int* in_sizes, int n_in,
                              void* d_out, int out_size, void* d_ws, size_t ws_size,
                              hipStream_t stream) {
    const int* edge_index = (const int*)d_in[0];   // (2, E) int32
    const int* etype      = (const int*)d_in[1];   // (E,)  int32
    const float* W1    = (const float*)d_in[2];    // (R,N,H) f32
    const float* root1 = (const float*)d_in[3];    // (N,H)
    const float* b1    = (const float*)d_in[4];    // (H,)
    const float* W2    = (const float*)d_in[5];    // (R,H,L)
    const float* root2 = (const float*)d_in[6];    // (H,L)
    const float* b2    = (const float*)d_in[7];    // (L,)
    float* out = (float*)d_out;                    // (N, L) f32

    const int* src = edge_index;       // row 0
    const int* dst = edge_index + Ee;  // row 1

    // workspace (int32 units):
    //   combo  [0,        800016)    fixup writes (ofs<<8|cnt + sentinel)
    //   csr32  [800016,   2400016)   scatter -> layers
    //   h1h    [2400016,  3200016)   N*H fp16, layer1 -> layer2
    //   counts [3200016,  4000016)   count -> scanned in place (intra-chunk)
    //   cur    [4000016,  4800016)   fixup -> scatter cursors
    //   bsum   [4800016,  4801040)
    //   boff   [4801040,  4802064)
    int* ws = (int*)d_ws;
    unsigned* combo        = (unsigned*)ws;
    unsigned* csr32        = (unsigned*)(ws + 800016);
    unsigned short* h1h    = (unsigned short*)(ws + 2400016);
    int* counts            = ws + 3200016;
    int* cur               = ws + 4000016;
    int* bsum              = ws + 4800016;
    int* boff              = ws + 4801040;

    if (ws_size < (size_t)4802064 * sizeof(int)) return;  // diagnostic guard

    hipMemsetAsync(counts, 0, (size_t)NSEG * sizeof(int), stream);

    const int nblkE  = (Ee / 4 + 255) / 256;      // 1563
    const int nblkL  = (Nn * 64 + 255) / 256;     // 12500 (wave per dst)

    count_kernel<<<nblkE, 256, 0, stream>>>(dst, etype, counts);
    scanA_kernel<<<NBLK_SC, 256, 0, stream>>>((int4*)counts, bsum);
    scanB_kernel<<<1, 1024, 0, stream>>>(bsum, boff, NBLK_SC);
    fixup_kernel<<<NBLK_SC, 256, 0, stream>>>((const int4*)counts, boff,
                                              combo, cur);
    scatter_kernel<<<nblkE, 256, 0, stream>>>(src, dst, etype, combo, cur,
                                              csr32);
    layer1_kernel<<<nblkL, 256, 0, stream>>>(csr32, combo, W1, root1, b1, h1h);
    layer2_kernel<<<nblkL, 256, 0, stream>>>(csr32, combo, h1h, W2, root2, b2,
                                             out);
}

// Round 5
// 298.695 us; speedup vs baseline: 1.3227x; 1.3227x over previous
//
#include <hip/hip_runtime.h>
#include <hip/hip_bf16.h>

// RGCN: N=50000, R=16, H=32, L=8, E=1600000. Float tensors f32; h1 fp16.
// Build (zero global atomics): two-level LDS bucket sort
// (p1hist -> scan1/scan2 -> p1scat -> p2sort) producing
// combo[seg]=(offs<<8)|cnt and csr32=(r<<24)|(k<<16)|src sorted by (dst,r).
// Round 14 = revert to round-12 state (verified 298.5us). Round-13's
// global-atomic scatter regressed 298->395us: 4B random csr32 stores caused
// ~16x write-line amplification (WRITE 106MB for 6.4MB payload, FETCH 57.8MB
// of RMW line fills). The LDS bucket sort's coalesced payload runs are the
// load-bearing feature; keep it.
// Layers: wave-per-dst, 32 edges in flight (4 pipelined gather clusters);
// layer2 inner loop on v_dot2_f32_f16 with W2/root2 in LDS as fp16 h-pairs.
#define Nn 50000
#define Rr 16
#define Hh 32
#define Ll 8
#define Ee 1600000
#define NSEG 800000
#define NB 782          // buckets = dst>>6
#define CH 4096         // edges per partition block
#define NBLK1 391       // ceil(E/CH)
#define COLS 392        // histT row stride
#define HT_INT4 76636   // NB*COLS/4
#define CAP 3072        // max edges per bucket
#define W2U 20          // LDS row stride in dwords (16 used + 4 pad)

typedef _Float16 h2 __attribute__((ext_vector_type(2)));

__device__ __forceinline__ float dot2(h2 a, unsigned b, float c) {
#ifdef __AMDGCN__
    return __builtin_amdgcn_fdot2(a, __builtin_bit_cast(h2, b), c, false);
#else
    h2 hb = __builtin_bit_cast(h2, b);
    return fmaf((float)a[0], (float)hb[0],
                fmaf((float)a[1], (float)hb[1], c));
#endif
}

// ---- pass 1a: per-block bucket histogram (LDS atomics only) ----
__global__ __launch_bounds__(256) void p1hist_kernel(
        const int* __restrict__ dst, int* __restrict__ histT) {
    __shared__ int hist[1024];
    for (int i = threadIdx.x; i < 1024; i += 256) hist[i] = 0;
    __syncthreads();
    int base = blockIdx.x * CH;
    int n = min(CH, Ee - base);
    for (int i = threadIdx.x; i < n; i += 256)
        atomicAdd(&hist[dst[base + i] >> 6], 1);
    __syncthreads();
    for (int k = threadIdx.x; k < NB; k += 256)
        histT[k * COLS + blockIdx.x] = hist[k];
}

// ---- scan1: per-1024-chunk exclusive prefix (in place) + chunk totals ----
__global__ __launch_bounds__(256) void scan1_kernel(
        int4* data4, int* __restrict__ bsum) {
    __shared__ int sm[256];
    int i4 = blockIdx.x * 256 + threadIdx.x;
    int4 v = make_int4(0, 0, 0, 0);
    if (i4 < HT_INT4) v = data4[i4];
    int s0 = v.x, s1 = s0 + v.y, s2 = s1 + v.z, s3 = s2 + v.w;
    sm[threadIdx.x] = s3;
    __syncthreads();
    for (int off = 1; off < 256; off <<= 1) {
        int add = (threadIdx.x >= off) ? sm[threadIdx.x - off] : 0;
        __syncthreads();
        sm[threadIdx.x] += add;
        __syncthreads();
    }
    int base = sm[threadIdx.x] - s3;
    if (i4 < HT_INT4)
        data4[i4] = make_int4(base, base + s0, base + s1, base + s2);
    if (threadIdx.x == 255) bsum[blockIdx.x] = sm[255];
}

// ---- scan2: exclusive prefix of chunk totals ----
__global__ __launch_bounds__(1024) void scan2_kernel(
        const int* __restrict__ bsum, int* __restrict__ boff, int nblk) {
    __shared__ int sm[1024];
    int v = (threadIdx.x < nblk) ? bsum[threadIdx.x] : 0;
    sm[threadIdx.x] = v;
    __syncthreads();
    for (int off = 1; off < 1024; off <<= 1) {
        int add = (threadIdx.x >= off) ? sm[threadIdx.x - off] : 0;
        __syncthreads();
        sm[threadIdx.x] += add;
        __syncthreads();
    }
    if (threadIdx.x < nblk) boff[threadIdx.x] = sm[threadIdx.x] - v;
}

// ---- pass 1b: rank in LDS, write bucket-grouped payload runs ----
// global offset of histT[idx] = histT[idx] (intra-chunk) + boff[idx>>10]
__global__ __launch_bounds__(256) void p1scat_kernel(
        const int* __restrict__ src, const int* __restrict__ dst,
        const int* __restrict__ etype, const int* __restrict__ offsT,
        const int* __restrict__ boff, unsigned* __restrict__ pay) {
    __shared__ int lhist[1024], lofs[1024], lcur[1024], goff[1024];
    __shared__ int partial[256];
    __shared__ unsigned stage[CH];
    __shared__ unsigned short sbkt[CH];
    int t = threadIdx.x;
    for (int i = t; i < 1024; i += 256) lhist[i] = 0;
    __syncthreads();
    int base = blockIdx.x * CH;
    int n = min(CH, Ee - base);
    for (int i = t; i < n; i += 256)
        atomicAdd(&lhist[dst[base + i] >> 6], 1);
    __syncthreads();
    int h0 = lhist[4*t], h1v = lhist[4*t+1], h2i = lhist[4*t+2], h3 = lhist[4*t+3];
    int s = h0 + h1v + h2i + h3;
    partial[t] = s;
    __syncthreads();
    for (int off = 1; off < 256; off <<= 1) {
        int add = (t >= off) ? partial[t - off] : 0;
        __syncthreads();
        partial[t] += add;
        __syncthreads();
    }
    int run = partial[t] - s;
    lofs[4*t] = run; lcur[4*t] = run; run += h0;
    lofs[4*t+1] = run; lcur[4*t+1] = run; run += h1v;
    lofs[4*t+2] = run; lcur[4*t+2] = run; run += h2i;
    lofs[4*t+3] = run; lcur[4*t+3] = run;
    for (int k = t; k < NB; k += 256) {
        int idx = k * COLS + blockIdx.x;
        goff[k] = offsT[idx] + boff[idx >> 10];
    }
    __syncthreads();
    for (int i = t; i < n; i += 256) {
        int e = base + i;
        int dv = dst[e];
        int b = dv >> 6;
        int pos = atomicAdd(&lcur[b], 1);
        stage[pos] = ((unsigned)(dv & 63) << 20) | ((unsigned)etype[e] << 16)
                   | (unsigned)src[e];
        sbkt[pos] = (unsigned short)b;
    }
    __syncthreads();
    for (int j = t; j < n; j += 256) {
        int b = sbkt[j];
        pay[goff[b] + (j - lofs[b])] = stage[j];
    }
}

// ---- pass 2: per-bucket counting sort, combo + csr32 (in place) ----
__global__ __launch_bounds__(256) void p2sort_kernel(
        const int* __restrict__ offsT, const int* __restrict__ boff,
        unsigned* pay, unsigned* __restrict__ combo) {
    __shared__ unsigned buf[CAP], outb[CAP];
    __shared__ int hist[1024], lofs[1024], lcur[1024], partial[256];
    int k = blockIdx.x, t = threadIdx.x;
    int idx0 = k * COLS;
    int base = offsT[idx0] + boff[idx0 >> 10];
    int next;
    if (k == NB - 1) {
        next = Ee;
    } else {
        int idx1 = (k + 1) * COLS;
        next = offsT[idx1] + boff[idx1 >> 10];
    }
    int n = next - base;
    for (int i = t; i < 1024; i += 256) hist[i] = 0;
    __syncthreads();
    for (int j = t; j < n; j += 256) {
        unsigned p = pay[base + j];
        buf[j] = p;
        atomicAdd(&hist[(p >> 16) & 0x3FFu], 1);
    }
    __syncthreads();
    int h0 = hist[4*t], h1v = hist[4*t+1], h2i = hist[4*t+2], h3 = hist[4*t+3];
    int s = h0 + h1v + h2i + h3;
    partial[t] = s;
    __syncthreads();
    for (int off = 1; off < 256; off <<= 1) {
        int add = (t >= off) ? partial[t - off] : 0;
        __syncthreads();
        partial[t] += add;
        __syncthreads();
    }
    int run = partial[t] - s;
    lofs[4*t] = run; lcur[4*t] = run; run += h0;
    lofs[4*t+1] = run; lcur[4*t+1] = run; run += h1v;
    lofs[4*t+2] = run; lcur[4*t+2] = run; run += h2i;
    lofs[4*t+3] = run; lcur[4*t+3] = run;
    __syncthreads();
    for (int bin = t; bin < 1024; bin += 256) {
        int dglob = (k << 6) | (bin >> 4);
        if (dglob < Nn)
            combo[(k << 10) | bin] =
                ((unsigned)(base + lofs[bin]) << 8) | (unsigned)hist[bin];
    }
    if (k == NB - 1 && t == 0) combo[NSEG] = ((unsigned)Ee) << 8;
    for (int j = t; j < n; j += 256) {
        unsigned p = buf[j];
        int bin = (int)((p >> 16) & 0x3FFu);
        int pos = atomicAdd(&lcur[bin], 1);
        outb[pos] = (((p >> 16) & 15u) << 24) | ((unsigned)hist[bin] << 16)
                  | (p & 0xFFFFu);
    }
    __syncthreads();
    for (int j = t; j < n; j += 256) pay[base + j] = outb[j];   // csr32
}

// ---- layer 1: wave per dst; 32 edges in flight (4 pipelined clusters) ----
__global__ __launch_bounds__(256) void layer1_kernel(
        const unsigned* __restrict__ csr32, const unsigned* __restrict__ combo,
        const float* __restrict__ W1, const float* __restrict__ root1,
        const float* __restrict__ b1, unsigned short* __restrict__ h1h) {
    int d = (blockIdx.x * 256 + threadIdx.x) >> 6;
    int lane = threadIdx.x & 63;
    int slot = lane >> 3, chunk = lane & 7;
    if (d >= Nn) return;
    int beg = (int)(combo[d << 4] >> 8);
    int end = (int)(combo[(d + 1) << 4] >> 8);
    int deg = end - beg;
    float4 acc = make_float4(0.f, 0.f, 0.f, 0.f);
    const float* Wc = W1 + (chunk << 2);
#pragma unroll 1
    for (int i = 0; i < deg; i += 32) {
        int p0 = i + slot, p1 = p0 + 8, p2 = p0 + 16, p3 = p0 + 24;
        bool r0 = p0 < deg, r1 = p1 < deg, r2 = p2 < deg, r3 = p3 < deg;
        unsigned v0 = csr32[beg + (r0 ? p0 : 0)];
        unsigned v1 = csr32[beg + (r1 ? p1 : 0)];
        unsigned v2 = csr32[beg + (r2 ? p2 : 0)];
        unsigned v3 = csr32[beg + (r3 ? p3 : 0)];
        float n0 = r0 ? __builtin_amdgcn_rcpf((float)((v0 >> 16) & 255u)) : 0.f;
        float n1 = r1 ? __builtin_amdgcn_rcpf((float)((v1 >> 16) & 255u)) : 0.f;
        float n2 = r2 ? __builtin_amdgcn_rcpf((float)((v2 >> 16) & 255u)) : 0.f;
        float n3 = r3 ? __builtin_amdgcn_rcpf((float)((v3 >> 16) & 255u)) : 0.f;
        float4 w0 = *(const float4*)(Wc +
            ((size_t)((int)(v0 >> 24) * Nn + (int)(v0 & 0xffffu)) << 5));
        float4 w1 = *(const float4*)(Wc +
            ((size_t)((int)(v1 >> 24) * Nn + (int)(v1 & 0xffffu)) << 5));
        float4 w2 = *(const float4*)(Wc +
            ((size_t)((int)(v2 >> 24) * Nn + (int)(v2 & 0xffffu)) << 5));
        float4 w3 = *(const float4*)(Wc +
            ((size_t)((int)(v3 >> 24) * Nn + (int)(v3 & 0xffffu)) << 5));
        acc.x = fmaf(n0, w0.x, acc.x); acc.y = fmaf(n0, w0.y, acc.y);
        acc.z = fmaf(n0, w0.z, acc.z); acc.w = fmaf(n0, w0.w, acc.w);
        acc.x = fmaf(n1, w1.x, acc.x); acc.y = fmaf(n1, w1.y, acc.y);
        acc.z = fmaf(n1, w1.z, acc.z); acc.w = fmaf(n1, w1.w, acc.w);
        acc.x = fmaf(n2, w2.x, acc.x); acc.y = fmaf(n2, w2.y, acc.y);
        acc.z = fmaf(n2, w2.z, acc.z); acc.w = fmaf(n2, w2.w, acc.w);
        acc.x = fmaf(n3, w3.x, acc.x); acc.y = fmaf(n3, w3.y, acc.y);
        acc.z = fmaf(n3, w3.z, acc.z); acc.w = fmaf(n3, w3.w, acc.w);
    }
#pragma unroll
    for (int m = 8; m <= 32; m <<= 1) {
        acc.x += __shfl_xor(acc.x, m, 64);
        acc.y += __shfl_xor(acc.y, m, 64);
        acc.z += __shfl_xor(acc.z, m, 64);
        acc.w += __shfl_xor(acc.w, m, 64);
    }
    if (slot == 0) {
        int hb = chunk << 2;
        float4 rt = *(const float4*)(root1 + (d << 5) + hb);
        float4 bb = *(const float4*)(b1 + hb);
        _Float16 q0 = (_Float16)fmaxf(acc.x + rt.x + bb.x, 0.f);
        _Float16 q1 = (_Float16)fmaxf(acc.y + rt.y + bb.y, 0.f);
        _Float16 q2 = (_Float16)fmaxf(acc.z + rt.z + bb.z, 0.f);
        _Float16 q3 = (_Float16)fmaxf(acc.w + rt.w + bb.w, 0.f);
        ushort4 ov;
        ov.x = __builtin_bit_cast(unsigned short, q0);
        ov.y = __builtin_bit_cast(unsigned short, q1);
        ov.z = __builtin_bit_cast(unsigned short, q2);
        ov.w = __builtin_bit_cast(unsigned short, q3);
        *(ushort4*)(h1h + (d << 5) + hb) = ov;
    }
}

// ---- layer 2: wave per dst; 32 edges in flight; fdot2 fp16 MAC (LDS) ----
__global__ __launch_bounds__(256) void layer2_kernel(
        const unsigned* __restrict__ csr32, const unsigned* __restrict__ combo,
        const unsigned short* __restrict__ h1h, const float* __restrict__ W2,
        const float* __restrict__ root2, const float* __restrict__ b2,
        float* __restrict__ out) {
    // W2s[(r*8+c)*W2U + hp*8 + l] = half2(W2[r][4c+2hp][l], W2[r][4c+2hp+1][l])
    // r==16 row holds root2. 16 dwords used per row, stride 20 (80B, 16B-aligned).
    __shared__ unsigned W2s[17 * 8 * W2U];
    for (int idx = threadIdx.x; idx < 17 * 8 * 16; idx += 256) {
        int r = idx >> 7;
        int c = (idx >> 4) & 7;
        int u = idx & 15;
        int hp = u >> 3, l = u & 7;
        int hh = (c << 2) | (hp << 1);
        float w0, w1;
        if (r < 16) {
            w0 = W2[(r << 8) + (hh << 3) + l];
            w1 = W2[(r << 8) + ((hh + 1) << 3) + l];
        } else {
            w0 = root2[(hh << 3) + l];
            w1 = root2[((hh + 1) << 3) + l];
        }
        h2 p = { (_Float16)w0, (_Float16)w1 };
        W2s[((r << 3) | c) * W2U + u] = __builtin_bit_cast(unsigned, p);
    }
    __syncthreads();

    int d = (blockIdx.x * 256 + threadIdx.x) >> 6;
    int lane = threadIdx.x & 63;
    int slot = lane >> 3, chunk = lane & 7;
    if (d >= Nn) return;
    int beg = (int)(combo[d << 4] >> 8);
    int end = (int)(combo[(d + 1) << 4] >> 8);
    int deg = end - beg;
    int degv = deg + 1;                 // + virtual root2 edge
    float acc[8] = {0.f, 0.f, 0.f, 0.f, 0.f, 0.f, 0.f, 0.f};
    const int hb = chunk << 2;
#pragma unroll 1
    for (int i = 0; i < degv; i += 32) {
        int p0 = i + slot, p1 = p0 + 8, p2 = p0 + 16, p3 = p0 + 24;
        bool re0 = p0 < deg, re1 = p1 < deg, re2 = p2 < deg, re3 = p3 < deg;
        bool vi0 = p0 == deg, vi1 = p1 == deg, vi2 = p2 == deg, vi3 = p3 == deg;
        unsigned v0 = csr32[beg + (re0 ? p0 : 0)];
        unsigned v1 = csr32[beg + (re1 ? p1 : 0)];
        unsigned v2 = csr32[beg + (re2 ? p2 : 0)];
        unsigned v3 = csr32[beg + (re3 ? p3 : 0)];
        int s0 = vi0 ? d : (re0 ? (int)(v0 & 0xffffu) : 0);
        int s1 = vi1 ? d : (re1 ? (int)(v1 & 0xffffu) : 0);
        int s2 = vi2 ? d : (re2 ? (int)(v2 & 0xffffu) : 0);
        int s3 = vi3 ? d : (re3 ? (int)(v3 & 0xffffu) : 0);
        int r0 = vi0 ? 16 : (re0 ? (int)(v0 >> 24) : 0);
        int r1 = vi1 ? 16 : (re1 ? (int)(v1 >> 24) : 0);
        int r2 = vi2 ? 16 : (re2 ? (int)(v2 >> 24) : 0);
        int r3 = vi3 ? 16 : (re3 ? (int)(v3 >> 24) : 0);
        float n0 = vi0 ? 1.0f
                 : (re0 ? __builtin_amdgcn_rcpf((float)((v0 >> 16) & 255u)) : 0.f);
        float n1 = vi1 ? 1.0f
                 : (re1 ? __builtin_amdgcn_rcpf((float)((v1 >> 16) & 255u)) : 0.f);
        float n2 = vi2 ? 1.0f
                 : (re2 ? __builtin_amdgcn_rcpf((float)((v2 >> 16) & 255u)) : 0.f);
        float n3 = vi3 ? 1.0f
                 : (re3 ? __builtin_amdgcn_rcpf((float)((v3 >> 16) & 255u)) : 0.f);
        uint2 hw0 = *(const uint2*)(h1h + (s0 << 5) + hb);
        uint2 hw1 = *(const uint2*)(h1h + (s1 << 5) + hb);
        uint2 hw2 = *(const uint2*)(h1h + (s2 << 5) + hb);
        uint2 hw3 = *(const uint2*)(h1h + (s3 << 5) + hb);
        const unsigned* w0p = &W2s[((r0 << 3) | chunk) * W2U];
        const unsigned* w1p = &W2s[((r1 << 3) | chunk) * W2U];
        const unsigned* w2p = &W2s[((r2 << 3) | chunk) * W2U];
        const unsigned* w3p = &W2s[((r3 << 3) | chunk) * W2U];

        h2 n0h = { (_Float16)n0, (_Float16)n0 };
        h2 a00 = __builtin_bit_cast(h2, hw0.x) * n0h;
        h2 a01 = __builtin_bit_cast(h2, hw0.y) * n0h;
        uint4 b00 = *(const uint4*)(w0p);
        uint4 b01 = *(const uint4*)(w0p + 4);
        uint4 b02 = *(const uint4*)(w0p + 8);
        uint4 b03 = *(const uint4*)(w0p + 12);
        acc[0] = dot2(a00, b00.x, acc[0]); acc[1] = dot2(a00, b00.y, acc[1]);
        acc[2] = dot2(a00, b00.z, acc[2]); acc[3] = dot2(a00, b00.w, acc[3]);
        acc[4] = dot2(a00, b01.x, acc[4]); acc[5] = dot2(a00, b01.y, acc[5]);
        acc[6] = dot2(a00, b01.z, acc[6]); acc[7] = dot2(a00, b01.w, acc[7]);
        acc[0] = dot2(a01, b02.x, acc[0]); acc[1] = dot2(a01, b02.y, acc[1]);
        acc[2] = dot2(a01, b02.z, acc[2]); acc[3] = dot2(a01, b02.w, acc[3]);
        acc[4] = dot2(a01, b03.x, acc[4]); acc[5] = dot2(a01, b03.y, acc[5]);
        acc[6] = dot2(a01, b03.z, acc[6]); acc[7] = dot2(a01, b03.w, acc[7]);

        h2 n1h = { (_Float16)n1, (_Float16)n1 };
        h2 a10 = __builtin_bit_cast(h2, hw1.x) * n1h;
        h2 a11 = __builtin_bit_cast(h2, hw1.y) * n1h;
        uint4 b10 = *(const uint4*)(w1p);
        uint4 b11 = *(const uint4*)(w1p + 4);
        uint4 b12 = *(const uint4*)(w1p + 8);
        uint4 b13 = *(const uint4*)(w1p + 12);
        acc[0] = dot2(a10, b10.x, acc[0]); acc[1] = dot2(a10, b10.y, acc[1]);
        acc[2] = dot2(a10, b10.z, acc[2]); acc[3] = dot2(a10, b10.w, acc[3]);
        acc[4] = dot2(a10, b11.x, acc[4]); acc[5] = dot2(a10, b11.y, acc[5]);
        acc[6] = dot2(a10, b11.z, acc[6]); acc[7] = dot2(a10, b11.w, acc[7]);
        acc[0] = dot2(a11, b12.x, acc[0]); acc[1] = dot2(a11, b12.y, acc[1]);
        acc[2] = dot2(a11, b12.z, acc[2]); acc[3] = dot2(a11, b12.w, acc[3]);
        acc[4] = dot2(a11, b13.x, acc[4]); acc[5] = dot2(a11, b13.y, acc[5]);
        acc[6] = dot2(a11, b13.z, acc[6]); acc[7] = dot2(a11, b13.w, acc[7]);

        h2 n2h = { (_Float16)n2, (_Float16)n2 };
        h2 a20 = __builtin_bit_cast(h2, hw2.x) * n2h;
        h2 a21 = __builtin_bit_cast(h2, hw2.y) * n2h;
        uint4 b20 = *(const uint4*)(w2p);
        uint4 b21 = *(const uint4*)(w2p + 4);
        uint4 b22 = *(const uint4*)(w2p + 8);
        uint4 b23 = *(const uint4*)(w2p + 12);
        acc[0] = dot2(a20, b20.x, acc[0]); acc[1] = dot2(a20, b20.y, acc[1]);
        acc[2] = dot2(a20, b20.z, acc[2]); acc[3] = dot2(a20, b20.w, acc[3]);
        acc[4] = dot2(a20, b21.x, acc[4]); acc[5] = dot2(a20, b21.y, acc[5]);
        acc[6] = dot2(a20, b21.z, acc[6]); acc[7] = dot2(a20, b21.w, acc[7]);
        acc[0] = dot2(a21, b22.x, acc[0]); acc[1] = dot2(a21, b22.y, acc[1]);
        acc[2] = dot2(a21, b22.z, acc[2]); acc[3] = dot2(a21, b22.w, acc[3]);
        acc[4] = dot2(a21, b23.x, acc[4]); acc[5] = dot2(a21, b23.y, acc[5]);
        acc[6] = dot2(a21, b23.z, acc[6]); acc[7] = dot2(a21, b23.w, acc[7]);

        h2 n3h = { (_Float16)n3, (_Float16)n3 };
        h2 a30 = __builtin_bit_cast(h2, hw3.x) * n3h;
        h2 a31 = __builtin_bit_cast(h2, hw3.y) * n3h;
        uint4 b30 = *(const uint4*)(w3p);
        uint4 b31 = *(const uint4*)(w3p + 4);
        uint4 b32 = *(const uint4*)(w3p + 8);
        uint4 b33 = *(const uint4*)(w3p + 12);
        acc[0] = dot2(a30, b30.x, acc[0]); acc[1] = dot2(a30, b30.y, acc[1]);
        acc[2] = dot2(a30, b30.z, acc[2]); acc[3] = dot2(a30, b30.w, acc[3]);
        acc[4] = dot2(a30, b31.x, acc[4]); acc[5] = dot2(a30, b31.y, acc[5]);
        acc[6] = dot2(a30, b31.z, acc[6]); acc[7] = dot2(a30, b31.w, acc[7]);
        acc[0] = dot2(a31, b32.x, acc[0]); acc[1] = dot2(a31, b32.y, acc[1]);
        acc[2] = dot2(a31, b32.z, acc[2]); acc[3] = dot2(a31, b32.w, acc[3]);
        acc[4] = dot2(a31, b33.x, acc[4]); acc[5] = dot2(a31, b33.y, acc[5]);
        acc[6] = dot2(a31, b33.z, acc[6]); acc[7] = dot2(a31, b33.w, acc[7]);
    }
#pragma unroll
    for (int m = 1; m <= 32; m <<= 1) {
#pragma unroll
        for (int l = 0; l < 8; ++l)
            acc[l] += __shfl_xor(acc[l], m, 64);
    }
    if (lane < 8) {
        float myv = acc[0];
#pragma unroll
        for (int l = 1; l < 8; ++l) myv = (lane == l) ? acc[l] : myv;
        float o = myv + b2[lane];
        out[(d << 3) | lane] = 1.0f / (1.0f + __expf(-o));
    }
}

extern "C" void kernel_launch(void* const* d_in, const int* in_sizes, int n_in,
                              void* d_out, int out_size, void* d_ws, size_t ws_size,
                              hipStream_t stream) {
    const int* edge_index = (const int*)d_in[0];   // (2, E) int32
    const int* etype      = (const int*)d_in[1];   // (E,)  int32
    const float* W1    = (const float*)d_in[2];    // (R,N,H) f32
    const float* root1 = (const float*)d_in[3];    // (N,H)
    const float* b1    = (const float*)d_in[4];    // (H,)
    const float* W2    = (const float*)d_in[5];    // (R,H,L)
    const float* root2 = (const float*)d_in[6];    // (H,L)
    const float* b2    = (const float*)d_in[7];    // (L,)
    float* out = (float*)d_out;                    // (N, L) f32

    const int* src = edge_index;       // row 0
    const int* dst = edge_index + Ee;  // row 1

    // workspace (int32 units):
    //   combo  [0,        800016)    p2sort writes; layers read (+sentinel)
    //   pay    [800016,   2400016)   p1scat -> p2sort (in-place csr32) -> layers
    //   h1h    [2400016,  3200016)   N*H fp16, layer1 -> layer2
    //   histT  [3200016,  3506560)   NB*COLS; scanned in place (intra-chunk)
    //   bsum   [3506560,  3506872)
    //   boff   [3506872,  3507184)
    int* ws = (int*)d_ws;
    unsigned* combo        = (unsigned*)ws;
    unsigned* pay          = (unsigned*)(ws + 800016);
    unsigned short* h1h    = (unsigned short*)(ws + 2400016);
    int* histT             = ws + 3200016;
    int* bsum              = ws + 3506560;
    int* boff              = ws + 3506872;

    if (ws_size < (size_t)3507184 * sizeof(int)) return;  // diagnostic guard

    hipMemsetAsync(histT, 0, (size_t)(NB * COLS) * sizeof(int), stream);

    const int nblkSc = (HT_INT4 + 255) / 256;     // 300
    const int nblkL  = (Nn * 64 + 255) / 256;     // 12500 (wave per dst)

    p1hist_kernel<<<NBLK1, 256, 0, stream>>>(dst, histT);
    scan1_kernel<<<nblkSc, 256, 0, stream>>>((int4*)histT, bsum);
    scan2_kernel<<<1, 1024, 0, stream>>>(bsum, boff, nblkSc);
    p1scat_kernel<<<NBLK1, 256, 0, stream>>>(src, dst, etype, histT, boff, pay);
    p2sort_kernel<<<NB, 256, 0, stream>>>(histT, boff, pay, combo);
    layer1_kernel<<<nblkL, 256, 0, stream>>>(pay, combo, W1, root1, b1, h1h);
    layer2_kernel<<<nblkL, 256, 0, stream>>>(pay, combo, h1h, W2, root2, b2, out);
}

// Round 6
// 297.476 us; speedup vs baseline: 1.3281x; 1.0041x over previous
//
#include <hip/hip_runtime.h>
#include <hip/hip_bf16.h>

// RGCN: N=50000, R=16, H=32, L=8, E=1600000. Float tensors f32; h1 fp16.
// Build (zero global atomics): two-level LDS bucket sort
// (p1hist -> scan1/scan2 -> p1scat -> p2sort) producing
// combo[seg]=(offs<<8)|cnt and csr32=(r<<24)|(k<<16)|src sorted by (dst,r).
// Round 15: layer2 wave reshaped 8slots x 8chunks -> 16slots x 4chunks.
// Round-5 PMC: layer2 60.4us @ VALUBusy 72% = VALU-issue-bound, dominated by
// per-edge setup (csr decode/cndmask/rcp/addr math) replicated across all
// chunk-lanes of a slot. 4 chunks halves the replication (per-edge setup
// 8x -> 4x redundant) while fdot2/ds_read/pk_mul per edge are unchanged;
// iteration granularity stays 32 edges so slot utilization is identical.
// W2s LDS rows restride to 36 dwords: bank=(4r+c)*4 mod 32 -> <=2-way (free).
// Layer1 untouched (gather-bound near its ~33us memory floor).
#define Nn 50000
#define Rr 16
#define Hh 32
#define Ll 8
#define Ee 1600000
#define NSEG 800000
#define NB 782          // buckets = dst>>6
#define CH 4096         // edges per partition block
#define NBLK1 391       // ceil(E/CH)
#define COLS 392        // histT row stride
#define HT_INT4 76636   // NB*COLS/4
#define CAP 3072        // max edges per bucket
#define W2U 36          // LDS row stride in dwords (32 used + 4 pad)

typedef _Float16 h2 __attribute__((ext_vector_type(2)));

__device__ __forceinline__ float dot2(h2 a, unsigned b, float c) {
#ifdef __AMDGCN__
    return __builtin_amdgcn_fdot2(a, __builtin_bit_cast(h2, b), c, false);
#else
    h2 hb = __builtin_bit_cast(h2, b);
    return fmaf((float)a[0], (float)hb[0],
                fmaf((float)a[1], (float)hb[1], c));
#endif
}

// ---- pass 1a: per-block bucket histogram (LDS atomics only) ----
__global__ __launch_bounds__(256) void p1hist_kernel(
        const int* __restrict__ dst, int* __restrict__ histT) {
    __shared__ int hist[1024];
    for (int i = threadIdx.x; i < 1024; i += 256) hist[i] = 0;
    __syncthreads();
    int base = blockIdx.x * CH;
    int n = min(CH, Ee - base);
    for (int i = threadIdx.x; i < n; i += 256)
        atomicAdd(&hist[dst[base + i] >> 6], 1);
    __syncthreads();
    for (int k = threadIdx.x; k < NB; k += 256)
        histT[k * COLS + blockIdx.x] = hist[k];
}

// ---- scan1: per-1024-chunk exclusive prefix (in place) + chunk totals ----
__global__ __launch_bounds__(256) void scan1_kernel(
        int4* data4, int* __restrict__ bsum) {
    __shared__ int sm[256];
    int i4 = blockIdx.x * 256 + threadIdx.x;
    int4 v = make_int4(0, 0, 0, 0);
    if (i4 < HT_INT4) v = data4[i4];
    int s0 = v.x, s1 = s0 + v.y, s2 = s1 + v.z, s3 = s2 + v.w;
    sm[threadIdx.x] = s3;
    __syncthreads();
    for (int off = 1; off < 256; off <<= 1) {
        int add = (threadIdx.x >= off) ? sm[threadIdx.x - off] : 0;
        __syncthreads();
        sm[threadIdx.x] += add;
        __syncthreads();
    }
    int base = sm[threadIdx.x] - s3;
    if (i4 < HT_INT4)
        data4[i4] = make_int4(base, base + s0, base + s1, base + s2);
    if (threadIdx.x == 255) bsum[blockIdx.x] = sm[255];
}

// ---- scan2: exclusive prefix of chunk totals ----
__global__ __launch_bounds__(1024) void scan2_kernel(
        const int* __restrict__ bsum, int* __restrict__ boff, int nblk) {
    __shared__ int sm[1024];
    int v = (threadIdx.x < nblk) ? bsum[threadIdx.x] : 0;
    sm[threadIdx.x] = v;
    __syncthreads();
    for (int off = 1; off < 1024; off <<= 1) {
        int add = (threadIdx.x >= off) ? sm[threadIdx.x - off] : 0;
        __syncthreads();
        sm[threadIdx.x] += add;
        __syncthreads();
    }
    if (threadIdx.x < nblk) boff[threadIdx.x] = sm[threadIdx.x] - v;
}

// ---- pass 1b: rank in LDS, write bucket-grouped payload runs ----
// global offset of histT[idx] = histT[idx] (intra-chunk) + boff[idx>>10]
__global__ __launch_bounds__(256) void p1scat_kernel(
        const int* __restrict__ src, const int* __restrict__ dst,
        const int* __restrict__ etype, const int* __restrict__ offsT,
        const int* __restrict__ boff, unsigned* __restrict__ pay) {
    __shared__ int lhist[1024], lofs[1024], lcur[1024], goff[1024];
    __shared__ int partial[256];
    __shared__ unsigned stage[CH];
    __shared__ unsigned short sbkt[CH];
    int t = threadIdx.x;
    for (int i = t; i < 1024; i += 256) lhist[i] = 0;
    __syncthreads();
    int base = blockIdx.x * CH;
    int n = min(CH, Ee - base);
    for (int i = t; i < n; i += 256)
        atomicAdd(&lhist[dst[base + i] >> 6], 1);
    __syncthreads();
    int h0 = lhist[4*t], h1v = lhist[4*t+1], h2i = lhist[4*t+2], h3 = lhist[4*t+3];
    int s = h0 + h1v + h2i + h3;
    partial[t] = s;
    __syncthreads();
    for (int off = 1; off < 256; off <<= 1) {
        int add = (t >= off) ? partial[t - off] : 0;
        __syncthreads();
        partial[t] += add;
        __syncthreads();
    }
    int run = partial[t] - s;
    lofs[4*t] = run; lcur[4*t] = run; run += h0;
    lofs[4*t+1] = run; lcur[4*t+1] = run; run += h1v;
    lofs[4*t+2] = run; lcur[4*t+2] = run; run += h2i;
    lofs[4*t+3] = run; lcur[4*t+3] = run;
    for (int k = t; k < NB; k += 256) {
        int idx = k * COLS + blockIdx.x;
        goff[k] = offsT[idx] + boff[idx >> 10];
    }
    __syncthreads();
    for (int i = t; i < n; i += 256) {
        int e = base + i;
        int dv = dst[e];
        int b = dv >> 6;
        int pos = atomicAdd(&lcur[b], 1);
        stage[pos] = ((unsigned)(dv & 63) << 20) | ((unsigned)etype[e] << 16)
                   | (unsigned)src[e];
        sbkt[pos] = (unsigned short)b;
    }
    __syncthreads();
    for (int j = t; j < n; j += 256) {
        int b = sbkt[j];
        pay[goff[b] + (j - lofs[b])] = stage[j];
    }
}

// ---- pass 2: per-bucket counting sort, combo + csr32 (in place) ----
__global__ __launch_bounds__(256) void p2sort_kernel(
        const int* __restrict__ offsT, const int* __restrict__ boff,
        unsigned* pay, unsigned* __restrict__ combo) {
    __shared__ unsigned buf[CAP], outb[CAP];
    __shared__ int hist[1024], lofs[1024], lcur[1024], partial[256];
    int k = blockIdx.x, t = threadIdx.x;
    int idx0 = k * COLS;
    int base = offsT[idx0] + boff[idx0 >> 10];
    int next;
    if (k == NB - 1) {
        next = Ee;
    } else {
        int idx1 = (k + 1) * COLS;
        next = offsT[idx1] + boff[idx1 >> 10];
    }
    int n = next - base;
    for (int i = t; i < 1024; i += 256) hist[i] = 0;
    __syncthreads();
    for (int j = t; j < n; j += 256) {
        unsigned p = pay[base + j];
        buf[j] = p;
        atomicAdd(&hist[(p >> 16) & 0x3FFu], 1);
    }
    __syncthreads();
    int h0 = hist[4*t], h1v = hist[4*t+1], h2i = hist[4*t+2], h3 = hist[4*t+3];
    int s = h0 + h1v + h2i + h3;
    partial[t] = s;
    __syncthreads();
    for (int off = 1; off < 256; off <<= 1) {
        int add = (t >= off) ? partial[t - off] : 0;
        __syncthreads();
        partial[t] += add;
        __syncthreads();
    }
    int run = partial[t] - s;
    lofs[4*t] = run; lcur[4*t] = run; run += h0;
    lofs[4*t+1] = run; lcur[4*t+1] = run; run += h1v;
    lofs[4*t+2] = run; lcur[4*t+2] = run; run += h2i;
    lofs[4*t+3] = run; lcur[4*t+3] = run;
    __syncthreads();
    for (int bin = t; bin < 1024; bin += 256) {
        int dglob = (k << 6) | (bin >> 4);
        if (dglob < Nn)
            combo[(k << 10) | bin] =
                ((unsigned)(base + lofs[bin]) << 8) | (unsigned)hist[bin];
    }
    if (k == NB - 1 && t == 0) combo[NSEG] = ((unsigned)Ee) << 8;
    for (int j = t; j < n; j += 256) {
        unsigned p = buf[j];
        int bin = (int)((p >> 16) & 0x3FFu);
        int pos = atomicAdd(&lcur[bin], 1);
        outb[pos] = (((p >> 16) & 15u) << 24) | ((unsigned)hist[bin] << 16)
                  | (p & 0xFFFFu);
    }
    __syncthreads();
    for (int j = t; j < n; j += 256) pay[base + j] = outb[j];   // csr32
}

// ---- layer 1: wave per dst; 32 edges in flight (4 pipelined clusters) ----
__global__ __launch_bounds__(256) void layer1_kernel(
        const unsigned* __restrict__ csr32, const unsigned* __restrict__ combo,
        const float* __restrict__ W1, const float* __restrict__ root1,
        const float* __restrict__ b1, unsigned short* __restrict__ h1h) {
    int d = (blockIdx.x * 256 + threadIdx.x) >> 6;
    int lane = threadIdx.x & 63;
    int slot = lane >> 3, chunk = lane & 7;
    if (d >= Nn) return;
    int beg = (int)(combo[d << 4] >> 8);
    int end = (int)(combo[(d + 1) << 4] >> 8);
    int deg = end - beg;
    float4 acc = make_float4(0.f, 0.f, 0.f, 0.f);
    const float* Wc = W1 + (chunk << 2);
#pragma unroll 1
    for (int i = 0; i < deg; i += 32) {
        int p0 = i + slot, p1 = p0 + 8, p2 = p0 + 16, p3 = p0 + 24;
        bool r0 = p0 < deg, r1 = p1 < deg, r2 = p2 < deg, r3 = p3 < deg;
        unsigned v0 = csr32[beg + (r0 ? p0 : 0)];
        unsigned v1 = csr32[beg + (r1 ? p1 : 0)];
        unsigned v2 = csr32[beg + (r2 ? p2 : 0)];
        unsigned v3 = csr32[beg + (r3 ? p3 : 0)];
        float n0 = r0 ? __builtin_amdgcn_rcpf((float)((v0 >> 16) & 255u)) : 0.f;
        float n1 = r1 ? __builtin_amdgcn_rcpf((float)((v1 >> 16) & 255u)) : 0.f;
        float n2 = r2 ? __builtin_amdgcn_rcpf((float)((v2 >> 16) & 255u)) : 0.f;
        float n3 = r3 ? __builtin_amdgcn_rcpf((float)((v3 >> 16) & 255u)) : 0.f;
        float4 w0 = *(const float4*)(Wc +
            ((size_t)((int)(v0 >> 24) * Nn + (int)(v0 & 0xffffu)) << 5));
        float4 w1 = *(const float4*)(Wc +
            ((size_t)((int)(v1 >> 24) * Nn + (int)(v1 & 0xffffu)) << 5));
        float4 w2 = *(const float4*)(Wc +
            ((size_t)((int)(v2 >> 24) * Nn + (int)(v2 & 0xffffu)) << 5));
        float4 w3 = *(const float4*)(Wc +
            ((size_t)((int)(v3 >> 24) * Nn + (int)(v3 & 0xffffu)) << 5));
        acc.x = fmaf(n0, w0.x, acc.x); acc.y = fmaf(n0, w0.y, acc.y);
        acc.z = fmaf(n0, w0.z, acc.z); acc.w = fmaf(n0, w0.w, acc.w);
        acc.x = fmaf(n1, w1.x, acc.x); acc.y = fmaf(n1, w1.y, acc.y);
        acc.z = fmaf(n1, w1.z, acc.z); acc.w = fmaf(n1, w1.w, acc.w);
        acc.x = fmaf(n2, w2.x, acc.x); acc.y = fmaf(n2, w2.y, acc.y);
        acc.z = fmaf(n2, w2.z, acc.z); acc.w = fmaf(n2, w2.w, acc.w);
        acc.x = fmaf(n3, w3.x, acc.x); acc.y = fmaf(n3, w3.y, acc.y);
        acc.z = fmaf(n3, w3.z, acc.z); acc.w = fmaf(n3, w3.w, acc.w);
    }
#pragma unroll
    for (int m = 8; m <= 32; m <<= 1) {
        acc.x += __shfl_xor(acc.x, m, 64);
        acc.y += __shfl_xor(acc.y, m, 64);
        acc.z += __shfl_xor(acc.z, m, 64);
        acc.w += __shfl_xor(acc.w, m, 64);
    }
    if (slot == 0) {
        int hb = chunk << 2;
        float4 rt = *(const float4*)(root1 + (d << 5) + hb);
        float4 bb = *(const float4*)(b1 + hb);
        _Float16 q0 = (_Float16)fmaxf(acc.x + rt.x + bb.x, 0.f);
        _Float16 q1 = (_Float16)fmaxf(acc.y + rt.y + bb.y, 0.f);
        _Float16 q2 = (_Float16)fmaxf(acc.z + rt.z + bb.z, 0.f);
        _Float16 q3 = (_Float16)fmaxf(acc.w + rt.w + bb.w, 0.f);
        ushort4 ov;
        ov.x = __builtin_bit_cast(unsigned short, q0);
        ov.y = __builtin_bit_cast(unsigned short, q1);
        ov.z = __builtin_bit_cast(unsigned short, q2);
        ov.w = __builtin_bit_cast(unsigned short, q3);
        *(ushort4*)(h1h + (d << 5) + hb) = ov;
    }
}

// ---- layer 2: wave per dst; 16 slots x 4 chunks; fdot2 fp16 MAC (LDS) ----
// Each chunk-lane covers 8 h (4 h-pairs); per-edge setup shared by 4 lanes
// instead of 8. 2 clusters -> 32 edges in flight per wave.
__global__ __launch_bounds__(256) void layer2_kernel(
        const unsigned* __restrict__ csr32, const unsigned* __restrict__ combo,
        const unsigned short* __restrict__ h1h, const float* __restrict__ W2,
        const float* __restrict__ root2, const float* __restrict__ b2,
        float* __restrict__ out) {
    // W2s[((r<<2)|c)*W2U + hp*8 + l] = half2(W2[r][8c+2hp][l], W2[r][8c+2hp+1][l])
    // r==16 row holds root2. 32 dwords used per row, stride 36 (144B,
    // 16B-aligned; bank=(4r+c)*4 mod 32 -> <=2-way aliasing, free).
    __shared__ unsigned W2s[17 * 4 * W2U];
    for (int idx = threadIdx.x; idx < 17 * 4 * 32; idx += 256) {
        int r = idx >> 7;
        int c = (idx >> 5) & 3;
        int u = idx & 31;              // hp*8 + l
        int hp = u >> 3, l = u & 7;
        int h = (c << 3) | (hp << 1);
        float w0, w1;
        if (r < 16) {
            w0 = W2[(r << 8) + (h << 3) + l];
            w1 = W2[(r << 8) + ((h + 1) << 3) + l];
        } else {
            w0 = root2[(h << 3) + l];
            w1 = root2[((h + 1) << 3) + l];
        }
        h2 p = { (_Float16)w0, (_Float16)w1 };
        W2s[((r << 2) | c) * W2U + u] = __builtin_bit_cast(unsigned, p);
    }
    __syncthreads();

    int d = (blockIdx.x * 256 + threadIdx.x) >> 6;
    int lane = threadIdx.x & 63;
    int slot = lane >> 2, chunk = lane & 3;   // 16 slots x 4 chunks
    if (d >= Nn) return;
    int beg = (int)(combo[d << 4] >> 8);
    int end = (int)(combo[(d + 1) << 4] >> 8);
    int deg = end - beg;
    int degv = deg + 1;                 // + virtual root2 edge
    float acc[8] = {0.f, 0.f, 0.f, 0.f, 0.f, 0.f, 0.f, 0.f};
    const int hb = chunk << 3;          // 8 halves (16B) per chunk
#pragma unroll 1
    for (int i = 0; i < degv; i += 32) {
        int p0 = i + slot, p1 = p0 + 16;
        bool re0 = p0 < deg, re1 = p1 < deg;
        bool vi0 = p0 == deg, vi1 = p1 == deg;
        unsigned v0 = csr32[beg + (re0 ? p0 : 0)];
        unsigned v1 = csr32[beg + (re1 ? p1 : 0)];
        int s0 = vi0 ? d : (re0 ? (int)(v0 & 0xffffu) : 0);
        int s1 = vi1 ? d : (re1 ? (int)(v1 & 0xffffu) : 0);
        int r0 = vi0 ? 16 : (re0 ? (int)(v0 >> 24) : 0);
        int r1 = vi1 ? 16 : (re1 ? (int)(v1 >> 24) : 0);
        float n0 = vi0 ? 1.0f
                 : (re0 ? __builtin_amdgcn_rcpf((float)((v0 >> 16) & 255u)) : 0.f);
        float n1 = vi1 ? 1.0f
                 : (re1 ? __builtin_amdgcn_rcpf((float)((v1 >> 16) & 255u)) : 0.f);
        uint4 hw0 = *(const uint4*)(h1h + (s0 << 5) + hb);
        uint4 hw1 = *(const uint4*)(h1h + (s1 << 5) + hb);
        const unsigned* w0p = &W2s[((r0 << 2) | chunk) * W2U];
        const unsigned* w1p = &W2s[((r1 << 2) | chunk) * W2U];

        h2 n0h = { (_Float16)n0, (_Float16)n0 };
        h2 a00 = __builtin_bit_cast(h2, hw0.x) * n0h;   // h[8c+0..1]
        h2 a01 = __builtin_bit_cast(h2, hw0.y) * n0h;   // h[8c+2..3]
        h2 a02 = __builtin_bit_cast(h2, hw0.z) * n0h;   // h[8c+4..5]
        h2 a03 = __builtin_bit_cast(h2, hw0.w) * n0h;   // h[8c+6..7]
        uint4 b00 = *(const uint4*)(w0p);        // hp0, l0-3
        uint4 b01 = *(const uint4*)(w0p + 4);    // hp0, l4-7
        uint4 b02 = *(const uint4*)(w0p + 8);    // hp1, l0-3
        uint4 b03 = *(const uint4*)(w0p + 12);   // hp1, l4-7
        acc[0] = dot2(a00, b00.x, acc[0]); acc[1] = dot2(a00, b00.y, acc[1]);
        acc[2] = dot2(a00, b00.z, acc[2]); acc[3] = dot2(a00, b00.w, acc[3]);
        acc[4] = dot2(a00, b01.x, acc[4]); acc[5] = dot2(a00, b01.y, acc[5]);
        acc[6] = dot2(a00, b01.z, acc[6]); acc[7] = dot2(a00, b01.w, acc[7]);
        acc[0] = dot2(a01, b02.x, acc[0]); acc[1] = dot2(a01, b02.y, acc[1]);
        acc[2] = dot2(a01, b02.z, acc[2]); acc[3] = dot2(a01, b02.w, acc[3]);
        acc[4] = dot2(a01, b03.x, acc[4]); acc[5] = dot2(a01, b03.y, acc[5]);
        acc[6] = dot2(a01, b03.z, acc[6]); acc[7] = dot2(a01, b03.w, acc[7]);
        uint4 b04 = *(const uint4*)(w0p + 16);   // hp2, l0-3
        uint4 b05 = *(const uint4*)(w0p + 20);   // hp2, l4-7
        uint4 b06 = *(const uint4*)(w0p + 24);   // hp3, l0-3
        uint4 b07 = *(const uint4*)(w0p + 28);   // hp3, l4-7
        acc[0] = dot2(a02, b04.x, acc[0]); acc[1] = dot2(a02, b04.y, acc[1]);
        acc[2] = dot2(a02, b04.z, acc[2]); acc[3] = dot2(a02, b04.w, acc[3]);
        acc[4] = dot2(a02, b05.x, acc[4]); acc[5] = dot2(a02, b05.y, acc[5]);
        acc[6] = dot2(a02, b05.z, acc[6]); acc[7] = dot2(a02, b05.w, acc[7]);
        acc[0] = dot2(a03, b06.x, acc[0]); acc[1] = dot2(a03, b06.y, acc[1]);
        acc[2] = dot2(a03, b06.z, acc[2]); acc[3] = dot2(a03, b06.w, acc[3]);
        acc[4] = dot2(a03, b07.x, acc[4]); acc[5] = dot2(a03, b07.y, acc[5]);
        acc[6] = dot2(a03, b07.z, acc[6]); acc[7] = dot2(a03, b07.w, acc[7]);

        h2 n1h = { (_Float16)n1, (_Float16)n1 };
        h2 a10 = __builtin_bit_cast(h2, hw1.x) * n1h;
        h2 a11 = __builtin_bit_cast(h2, hw1.y) * n1h;
        h2 a12 = __builtin_bit_cast(h2, hw1.z) * n1h;
        h2 a13 = __builtin_bit_cast(h2, hw1.w) * n1h;
        uint4 b10 = *(const uint4*)(w1p);
        uint4 b11 = *(const uint4*)(w1p + 4);
        uint4 b12 = *(const uint4*)(w1p + 8);
        uint4 b13 = *(const uint4*)(w1p + 12);
        acc[0] = dot2(a10, b10.x, acc[0]); acc[1] = dot2(a10, b10.y, acc[1]);
        acc[2] = dot2(a10, b10.z, acc[2]); acc[3] = dot2(a10, b10.w, acc[3]);
        acc[4] = dot2(a10, b11.x, acc[4]); acc[5] = dot2(a10, b11.y, acc[5]);
        acc[6] = dot2(a10, b11.z, acc[6]); acc[7] = dot2(a10, b11.w, acc[7]);
        acc[0] = dot2(a11, b12.x, acc[0]); acc[1] = dot2(a11, b12.y, acc[1]);
        acc[2] = dot2(a11, b12.z, acc[2]); acc[3] = dot2(a11, b12.w, acc[3]);
        acc[4] = dot2(a11, b13.x, acc[4]); acc[5] = dot2(a11, b13.y, acc[5]);
        acc[6] = dot2(a11, b13.z, acc[6]); acc[7] = dot2(a11, b13.w, acc[7]);
        uint4 b14 = *(const uint4*)(w1p + 16);
        uint4 b15 = *(const uint4*)(w1p + 20);
        uint4 b16 = *(const uint4*)(w1p + 24);
        uint4 b17 = *(const uint4*)(w1p + 28);
        acc[0] = dot2(a12, b14.x, acc[0]); acc[1] = dot2(a12, b14.y, acc[1]);
        acc[2] = dot2(a12, b14.z, acc[2]); acc[3] = dot2(a12, b14.w, acc[3]);
        acc[4] = dot2(a12, b15.x, acc[4]); acc[5] = dot2(a12, b15.y, acc[5]);
        acc[6] = dot2(a12, b15.z, acc[6]); acc[7] = dot2(a12, b15.w, acc[7]);
        acc[0] = dot2(a13, b16.x, acc[0]); acc[1] = dot2(a13, b16.y, acc[1]);
        acc[2] = dot2(a13, b16.z, acc[2]); acc[3] = dot2(a13, b16.w, acc[3]);
        acc[4] = dot2(a13, b17.x, acc[4]); acc[5] = dot2(a13, b17.y, acc[5]);
        acc[6] = dot2(a13, b17.z, acc[6]); acc[7] = dot2(a13, b17.w, acc[7]);
    }
#pragma unroll
    for (int m = 1; m <= 32; m <<= 1) {
#pragma unroll
        for (int l = 0; l < 8; ++l)
            acc[l] += __shfl_xor(acc[l], m, 64);
    }
    if (lane < 8) {
        float myv = acc[0];
#pragma unroll
        for (int l = 1; l < 8; ++l) myv = (lane == l) ? acc[l] : myv;
        float o = myv + b2[lane];
        out[(d << 3) | lane] = 1.0f / (1.0f + __expf(-o));
    }
}

extern "C" void kernel_launch(void* const* d_in, const int* in_sizes, int n_in,
                              void* d_out, int out_size, void* d_ws, size_t ws_size,
                              hipStream_t stream) {
    const int* edge_index = (const int*)d_in[0];   // (2, E) int32
    const int* etype      = (const int*)d_in[1];   // (E,)  int32
    const float* W1    = (const float*)d_in[2];    // (R,N,H) f32
    const float* root1 = (const float*)d_in[3];    // (N,H)
    const float* b1    = (const float*)d_in[4];    // (H,)
    const float* W2    = (const float*)d_in[5];    // (R,H,L)
    const float* root2 = (const float*)d_in[6];    // (H,L)
    const float* b2    = (const float*)d_in[7];    // (L,)
    float* out = (float*)d_out;                    // (N, L) f32

    const int* src = edge_index;       // row 0
    const int* dst = edge_index + Ee;  // row 1

    // workspace (int32 units):
    //   combo  [0,        800016)    p2sort writes; layers read (+sentinel)
    //   pay    [800016,   2400016)   p1scat -> p2sort (in-place csr32) -> layers
    //   h1h    [2400016,  3200016)   N*H fp16, layer1 -> layer2
    //   histT  [3200016,  3506560)   NB*COLS; scanned in place (intra-chunk)
    //   bsum   [3506560,  3506872)
    //   boff   [3506872,  3507184)
    int* ws = (int*)d_ws;
    unsigned* combo        = (unsigned*)ws;
    unsigned* pay          = (unsigned*)(ws + 800016);
    unsigned short* h1h    = (unsigned short*)(ws + 2400016);
    int* histT             = ws + 3200016;
    int* bsum              = ws + 3506560;
    int* boff              = ws + 3506872;

    if (ws_size < (size_t)3507184 * sizeof(int)) return;  // diagnostic guard

    hipMemsetAsync(histT, 0, (size_t)(NB * COLS) * sizeof(int), stream);

    const int nblkSc = (HT_INT4 + 255) / 256;     // 300
    const int nblkL  = (Nn * 64 + 255) / 256;     // 12500 (wave per dst)

    p1hist_kernel<<<NBLK1, 256, 0, stream>>>(dst, histT);
    scan1_kernel<<<nblkSc, 256, 0, stream>>>((int4*)histT, bsum);
    scan2_kernel<<<1, 1024, 0, stream>>>(bsum, boff, nblkSc);
    p1scat_kernel<<<NBLK1, 256, 0, stream>>>(src, dst, etype, histT, boff, pay);
    p2sort_kernel<<<NB, 256, 0, stream>>>(histT, boff, pay, combo);
    layer1_kernel<<<nblkL, 256, 0, stream>>>(pay, combo, W1, root1, b1, h1h);
    layer2_kernel<<<nblkL, 256, 0, stream>>>(pay, combo, h1h, W2, root2, b2, out);
}